// Round 9
// baseline (21732.050 us; speedup 1.0000x reference)
//
#include <hip/hip_runtime.h>
#include <hip/hip_fp16.h>

// LSTM: B=64, T=2048, D=128, U=256.
// Phase 1: xz = inputs @ Wx (f32 tiled GEMM) -- R1/R3-proven, unchanged.
// Phase 2 (R9 rewrite): one WG per batch, 512 threads (8 waves).
//   z = h @ Wh via v_mfma_f32_16x16x32_f16, M=1 (row 0 used; A filled
//   uniformly so ALL C rows = z -- only the m89-verified C col=lane&15
//   mapping matters). 64 N-tiles x 8 K-tiles = 512 MFMA/step, 64/wave.
//   B-tiles per wave: 28 in AGPRs ("+a" pinned -- MFMA reads AGPR B natively,
//   R7 proved "a"-class residency works; its volatile-READ tax is gone),
//   18 in arch VGPRs, 18 in LDS (147KB static, R8-proven size). Zero scratch.

#define NB 64
#define NT 2048
#define ND 128
#define NU 256
#define N4U 1024

#define QA 28            // q < QA            -> AGPR tiles
#define QV 46            // QA <= q < QV      -> arch VGPR tiles (18)
#define NLDS (64 - QV)   // q >= QV           -> LDS tiles (18)

typedef _Float16 f16;
typedef _Float16 f16x8 __attribute__((ext_vector_type(8)));
typedef float f32x4 __attribute__((ext_vector_type(4)));

__device__ __forceinline__ float sigm(float x) { return 1.0f / (1.0f + __expf(-x)); }
__device__ __forceinline__ float tanh_(float x) { return 1.0f - 2.0f / (__expf(2.0f * x) + 1.0f); }

// ---------------- Phase 1: xz[b][t - t0][j] = sum_k X[b][t][k] * Wx[k][j] ----
__global__ __launch_bounds__(256) void xz_gemm(const float* __restrict__ X,
                                               const float* __restrict__ Wx,
                                               float* __restrict__ XZ,
                                               int t0, int tc) {
  __shared__ __align__(16) float xs[64][ND];   // [row][k] 32KB
  __shared__ __align__(16) float ws[ND][64];   // [k][col] 32KB
  const int tid = threadIdx.x;
  const int b = blockIdx.y;
  const int row0 = t0 + blockIdx.x * 64;
  const int col0 = blockIdx.z * 64;

  {
    const float* src = X + ((size_t)b * NT + row0) * ND;
#pragma unroll
    for (int ii = 0; ii < 8; ++ii) {
      int q = tid + 256 * ii;
      int r = q >> 5;
      int k4 = q & 31;
      f32x4 v = *(const f32x4*)(src + (size_t)r * ND + 4 * k4);
      *(f32x4*)&xs[r][4 * k4] = v;
    }
#pragma unroll
    for (int ii = 0; ii < 8; ++ii) {
      int q = tid + 256 * ii;
      int k = q >> 4;
      int c4 = q & 15;
      f32x4 v = *(const f32x4*)(Wx + (size_t)k * N4U + col0 + 4 * c4);
      *(f32x4*)&ws[k][4 * c4] = v;
    }
  }
  __syncthreads();

  const int tx = tid & 15, ty = tid >> 4;
  float acc[4][4];
#pragma unroll
  for (int i = 0; i < 4; ++i)
#pragma unroll
    for (int j = 0; j < 4; ++j) acc[i][j] = 0.0f;

#pragma unroll 8
  for (int k = 0; k < ND; ++k) {
    f32x4 bv = *(const f32x4*)&ws[k][4 * tx];
    float a0 = xs[4 * ty + 0][k];
    float a1 = xs[4 * ty + 1][k];
    float a2 = xs[4 * ty + 2][k];
    float a3 = xs[4 * ty + 3][k];
#pragma unroll
    for (int j = 0; j < 4; ++j) {
      acc[0][j] += a0 * bv[j];
      acc[1][j] += a1 * bv[j];
      acc[2][j] += a2 * bv[j];
      acc[3][j] += a3 * bv[j];
    }
  }

  float* dst = XZ + ((size_t)b * tc + (row0 - t0)) * N4U + col0;
#pragma unroll
  for (int i = 0; i < 4; ++i) {
    f32x4 v;
#pragma unroll
    for (int j = 0; j < 4; ++j) v[j] = acc[i][j];
    *(f32x4*)(dst + (size_t)(4 * ty + i) * N4U + 4 * tx) = v;
  }
}

// ---------------- Phase 2: MFMA sequential scan, one WG per batch -----------

// load B-tile (n_global, kt): element e = Wh[kt*32 + (lane>>4)*8 + e][ng*16 + (lane&15)]
__device__ __forceinline__ f16x8 load_btile(const float* __restrict__ Wh,
                                            int ng, int kt, int lane) {
  const int col = ng * 16 + (lane & 15);
  const int kb = kt * 32 + ((lane >> 4) << 3);
  f16x8 w;
#pragma unroll
  for (int e = 0; e < 8; ++e)
    w[e] = (f16)Wh[(size_t)(kb + e) * N4U + col];
  return w;
}

#define PINA7(i) asm volatile("" : "+a"(ba[i]), "+a"(ba[i+1]), "+a"(ba[i+2]), \
                                   "+a"(ba[i+3]), "+a"(ba[i+4]), "+a"(ba[i+5]), "+a"(ba[i+6]))
#define PINV6(i) asm volatile("" : "+v"(bv[i]), "+v"(bv[i+1]), "+v"(bv[i+2]), \
                                   "+v"(bv[i+3]), "+v"(bv[i+4]), "+v"(bv[i+5]))

__global__ __launch_bounds__(512, 1) void lstm_seq(const float* __restrict__ Wh,
                                                   const float* __restrict__ bias,
                                                   const float* __restrict__ XZ,
                                                   float* __restrict__ out,
                                                   float* __restrict__ state,
                                                   int t0, int tc) {
  __shared__ __align__(16) f16x8 wlds[NLDS][512];  // 147456 B
  __shared__ float zbuf[N4U];                      // 4096 B
  __shared__ __align__(16) f16 hbuf[NU];           // 512 B   (total 152064, R8-proven)

  const int tid = threadIdx.x;
  const int lane = tid & 63;
  const int wave = tid >> 6;
  const int b = blockIdx.x;

  // ---- B-tile residency: q = kt*8 + nl, ng = wave*8 + nl ----
  f16x8 ba[QA];
#pragma unroll
  for (int q = 0; q < QA; ++q)
    ba[q] = load_btile(Wh, wave * 8 + (q & 7), q >> 3, lane);
  PINA7(0); PINA7(7); PINA7(14); PINA7(21);        // set AGPR class

  f16x8 bv[QV - QA];
#pragma unroll
  for (int q = QA; q < QV; ++q)
    bv[q - QA] = load_btile(Wh, wave * 8 + (q & 7), q >> 3, lane);

#pragma unroll
  for (int q = QV; q < 64; ++q)
    wlds[q - QV][tid] = load_btile(Wh, wave * 8 + (q & 7), q >> 3, lane);

  // ---- gate-thread setup (threads 0..255) ----
  float b0 = 0.f, b1 = 0.f, b2 = 0.f, b3 = 0.f;
  float creg = 0.0f, hreg = 0.0f;
  if (tid < NU) {
    b0 = bias[tid];
    b1 = bias[tid + 256];
    b2 = bias[tid + 512];
    b3 = bias[tid + 768];
    if (t0 != 0) {
      hreg = state[(size_t)b * 2 * NU + tid];
      creg = state[(size_t)b * 2 * NU + NU + tid];
    }
    hbuf[tid] = (f16)hreg;
  }
  __syncthreads();   // wlds + hbuf ready

  const float* xzp = XZ + (size_t)b * tc * N4U;
  float x0 = 0.f, x1 = 0.f, x2 = 0.f, x3 = 0.f;
  if (tid < NU) {
    x0 = xzp[tid];
    x1 = xzp[tid + 256];
    x2 = xzp[tid + 512];
    x3 = xzp[tid + 768];
  }

  const f32x4 ZERO4 = {0.f, 0.f, 0.f, 0.f};

  for (int s = 0; s < tc; ++s) {
    // keep B tiles resident (re-defined each iter; empty asm, zero instrs)
    PINA7(0); PINA7(7); PINA7(14); PINA7(21);
    PINV6(0); PINV6(6); PINV6(12);

    f32x4 ca[8];
#pragma unroll
    for (int n = 0; n < 8; ++n) ca[n] = ZERO4;

    const f16x8* hb = (const f16x8*)hbuf;
#pragma unroll
    for (int kt = 0; kt < 8; ++kt) {
      f16x8 a = hb[kt * 4 + (lane >> 4)];   // uniform per 16-lane group -> all C rows = z
#pragma unroll
      for (int n = 0; n < 8; ++n) {
        const int q = kt * 8 + n;
        f16x8 bb;
        if (q < QA)       bb = ba[q];
        else if (q < QV)  bb = bv[q - QA];
        else              bb = wlds[q - QV][tid];
        ca[n] = __builtin_amdgcn_mfma_f32_16x16x32_f16(a, bb, ca[n], 0, 0, 0);
      }
    }

    if (lane < 16) {
#pragma unroll
      for (int n = 0; n < 8; ++n)
        zbuf[(wave * 8 + n) * 16 + lane] = ca[n][0];   // C col = lane&15 (m89-verified)
    }
    __syncthreads();   // zbuf ready; all A-reads of hbuf done

    if (tid < NU) {
      float zi = zbuf[tid]       + x0 + b0;
      float zf = zbuf[tid + 256] + x1 + b1;
      float zg = zbuf[tid + 512] + x2 + b2;
      float zo = zbuf[tid + 768] + x3 + b3;
      if (s + 1 < tc) {   // prefetch next step's xz (in flight during next MFMA phase)
        const float* xn = xzp + (size_t)(s + 1) * N4U;
        x0 = xn[tid];
        x1 = xn[tid + 256];
        x2 = xn[tid + 512];
        x3 = xn[tid + 768];
      }
      float ig = sigm(zi), fg = sigm(zf), og = sigm(zo), gg = tanh_(zg);
      creg = fg * creg + ig * gg;
      hreg = og * tanh_(creg);
      out[((size_t)b * NT + t0 + s) * NU + tid] = hreg;
      hbuf[tid] = (f16)hreg;
    }
    __syncthreads();   // hbuf ready for s+1; zbuf consumed
  }

  if (tid < NU) {
    state[(size_t)b * 2 * NU + tid] = hreg;
    state[(size_t)b * 2 * NU + NU + tid] = creg;
  }
}

extern "C" void kernel_launch(void* const* d_in, const int* in_sizes, int n_in,
                              void* d_out, int out_size, void* d_ws, size_t ws_size,
                              hipStream_t stream) {
  const float* inputs = (const float*)d_in[0];  // [64,2048,128]
  const float* Wx     = (const float*)d_in[1];  // [128,1024]
  const float* Wh     = (const float*)d_in[2];  // [256,1024]
  const float* bias   = (const float*)d_in[3];  // [1024]
  float* out = (float*)d_out;                   // [64,2048,256]

  const size_t state_bytes = (size_t)NB * 2 * NU * sizeof(float);  // 128KB
  float* state = (float*)d_ws;
  float* xzbuf = (float*)((char*)d_ws + state_bytes);

  size_t avail = (ws_size > state_bytes) ? (ws_size - state_bytes) : 0;
  size_t step_bytes = (size_t)NB * N4U * sizeof(float);  // 256KB per timestep
  long tc_l = (long)(avail / step_bytes);
  int tc = (tc_l > NT) ? NT : (int)tc_l;
  tc = (tc / 64) * 64;
  if (tc < 64) tc = 64;

  for (int t0 = 0; t0 < NT; t0 += tc) {
    int cur = NT - t0;
    if (cur > tc) cur = tc;
    dim3 g1(cur >> 6, NB, 16);
    xz_gemm<<<g1, 256, 0, stream>>>(inputs, Wx, xzbuf, t0, cur);
    lstm_seq<<<NB, 512, 0, stream>>>(Wh, bias, xzbuf, out, state, t0, cur);
  }
}